// Round 1
// baseline (147.619 us; speedup 1.0000x reference)
//
#include <hip/hip_runtime.h>
#include <cmath>

// CapsuleLayer dynamic routing, B=64, Ni=2048, Di=16, No=32, Do=16 (fp32).
// Insight: intermediate squash outputs are dead; b-logit updates are local to
// (b,n) given hsum = sum_d uhat. So compute c2 cheaply from d-reduced weights,
// then do the big uhat GEMM exactly once, fused with the final weighted sum.

#define NI 2048

// ---------------- Kernel 1: routing coefficients c2[b][n][o] ----------------
__global__ __launch_bounds__(256) void caps_c2_kernel(
    const float* __restrict__ x, const float* __restrict__ W,
    float* __restrict__ c2out)
{
  const int n = blockIdx.x;
  const int t = threadIdx.x;
  __shared__ __align__(16) float Wd[512];     // [o*16+i] = sum_d W[n][o][d][i]
  __shared__ __align__(16) float xs[64*17];   // [b*17+i] (pad 17: bank spread)
  __shared__ __align__(16) float c2s[2048];   // [b*32+o]

  #pragma unroll
  for (int p0 = 0; p0 < 2; ++p0) {
    int p = t + 256*p0;
    int o = p >> 4, i = p & 15;
    const float* wp = W + (size_t)n*8192 + o*256 + i;
    float acc = 0.f;
    #pragma unroll
    for (int d = 0; d < 16; ++d) acc += wp[d*16];
    Wd[p] = acc;
  }
  #pragma unroll
  for (int p0 = 0; p0 < 4; ++p0) {
    int p = t + 256*p0;
    int b = p >> 4, i = p & 15;
    xs[b*17 + i] = x[(size_t)b*(NI*16) + n*16 + i];
  }
  __syncthreads();

  // thread -> b = t>>2, quad-lane oq = t&3 covers o = oq + 4*jj
  const int b = t >> 2, oq = t & 3;
  float h[8];
  #pragma unroll
  for (int jj = 0; jj < 8; ++jj) {
    const int o = oq + 4*jj;
    float acc = 0.f;
    #pragma unroll
    for (int i = 0; i < 16; ++i) acc += Wd[o*16 + i] * xs[b*17 + i];
    h[jj] = acc;
  }
  // routing: b1 = h/32; c1 = softmax(b1); b2 = b1 + c1*h; c2 = softmax(b2)
  float b1[8], e[8];
  float mx = -1e30f;
  #pragma unroll
  for (int jj = 0; jj < 8; ++jj) { b1[jj] = h[jj]*0.03125f; mx = fmaxf(mx, b1[jj]); }
  mx = fmaxf(mx, __shfl_xor(mx, 1)); mx = fmaxf(mx, __shfl_xor(mx, 2));
  float S = 0.f;
  #pragma unroll
  for (int jj = 0; jj < 8; ++jj) { e[jj] = __expf(b1[jj]-mx); S += e[jj]; }
  S += __shfl_xor(S,1); S += __shfl_xor(S,2);
  float inv = 1.0f/S;
  float b2[8];
  float mx2 = -1e30f;
  #pragma unroll
  for (int jj = 0; jj < 8; ++jj) { b2[jj] = b1[jj] + e[jj]*inv*h[jj]; mx2 = fmaxf(mx2, b2[jj]); }
  mx2 = fmaxf(mx2, __shfl_xor(mx2,1)); mx2 = fmaxf(mx2, __shfl_xor(mx2,2));
  float S2 = 0.f;
  #pragma unroll
  for (int jj = 0; jj < 8; ++jj) { e[jj] = __expf(b2[jj]-mx2); S2 += e[jj]; }
  S2 += __shfl_xor(S2,1); S2 += __shfl_xor(S2,2);
  float inv2 = 1.0f/S2;
  #pragma unroll
  for (int jj = 0; jj < 8; ++jj) c2s[b*32 + oq + 4*jj] = e[jj]*inv2;
  __syncthreads();
  #pragma unroll
  for (int p0 = 0; p0 < 8; ++p0) {
    int p = t + 256*p0;
    c2out[(size_t)(p>>5)*(NI*32) + n*32 + (p&31)] = c2s[p];
  }
}

// ---------------- Kernel 2: fused uhat GEMM + c2-weighted sum ----------------
// Block: 512 threads = 8 waves (each wave: 8 b's), covers one o-half (256 cells),
// loops over NG=8 n's. Thread g covers cells {2g, 2g+1, 2g+128, 2g+129} (local).
#define NG 8
__global__ __launch_bounds__(512, 4) void caps_main_kernel(
    const float* __restrict__ x, const float* __restrict__ W,
    const float* __restrict__ c2, float* __restrict__ partial)
{
  const int gidx = blockIdx.x >> 1;   // n-group 0..255
  const int hh   = blockIdx.x & 1;    // o-half
  const int t = threadIdx.x;
  const int g = t & 63, bg = t >> 6;

  __shared__ __align__(16) float Wl[16*258];  // [k][cell_local], stride 258
  __shared__ __align__(16) float Xl[16*66];   // [k][b], stride 66
  __shared__ __align__(16) float Cl[2048];    // c2 [b*32+o]

  float sacc[8][4];
  #pragma unroll
  for (int l = 0; l < 8; ++l)
    #pragma unroll
    for (int c = 0; c < 4; ++c) sacc[l][c] = 0.f;

  #pragma unroll 1
  for (int nn = 0; nn < NG; ++nn) {
    const int n = gidx*NG + nn;
    // stage W half, transposed to k-major (pad 258 keeps banks clean)
    #pragma unroll
    for (int m2 = 0; m2 < 2; ++m2) {
      int q = t + 512*m2;
      float4 v = *(const float4*)(W + (size_t)n*8192 + hh*4096 + 4*q);
      int cell = q >> 2, kb = 4*(q & 3);
      Wl[(kb+0)*258 + cell] = v.x;
      Wl[(kb+1)*258 + cell] = v.y;
      Wl[(kb+2)*258 + cell] = v.z;
      Wl[(kb+3)*258 + cell] = v.w;
    }
    {
      int i = t & 15, b0 = t >> 4;
      #pragma unroll
      for (int m2 = 0; m2 < 2; ++m2) {
        int b = b0 + 32*m2;
        Xl[i*66 + b] = x[(size_t)b*(NI*16) + n*16 + i];
      }
    }
    #pragma unroll
    for (int m2 = 0; m2 < 4; ++m2) {
      int p = t + 512*m2;
      Cl[p] = c2[(size_t)(p>>5)*(NI*32) + n*32 + (p&31)];
    }
    __syncthreads();

    float acc[8][4];
    #pragma unroll
    for (int l = 0; l < 8; ++l)
      #pragma unroll
      for (int c = 0; c < 4; ++c) acc[l][c] = 0.f;

    #pragma unroll
    for (int k = 0; k < 16; ++k) {
      float2 w0 = *(const float2*)&Wl[k*258 + 2*g];        // cells 2g,2g+1
      float2 w1 = *(const float2*)&Wl[k*258 + 2*g + 128];  // cells +128
      const float* xp = &Xl[k*66 + bg*8];
      #pragma unroll
      for (int l = 0; l < 8; ++l) {
        float xv = xp[l];   // wave-uniform broadcast
        acc[l][0] += xv*w0.x; acc[l][1] += xv*w0.y;
        acc[l][2] += xv*w1.x; acc[l][3] += xv*w1.y;
      }
    }
    // weight by c2 and accumulate into persistent sacc
    const int o0 = (g >> 3);            // o_local for j=0; +8 for j=1
    #pragma unroll
    for (int l = 0; l < 8; ++l) {
      int b = bg*8 + l;
      float cA = Cl[b*32 + hh*16 + o0];
      float cB = Cl[b*32 + hh*16 + o0 + 8];
      sacc[l][0] += cA*acc[l][0]; sacc[l][1] += cA*acc[l][1];
      sacc[l][2] += cB*acc[l][2]; sacc[l][3] += cB*acc[l][3];
    }
    __syncthreads();
  }
  // write group partials: partial[gidx][b][cell] (cell = hh*256 + cell_local)
  #pragma unroll
  for (int l = 0; l < 8; ++l) {
    int b = bg*8 + l;
    size_t base = (size_t)gidx*32768 + (size_t)b*512 + hh*256;
    *(float2*)(partial + base + 2*g)       = make_float2(sacc[l][0], sacc[l][1]);
    *(float2*)(partial + base + 2*g + 128) = make_float2(sacc[l][2], sacc[l][3]);
  }
}

// ---------------- Kernel 3: reduce 256 partials + squash ----------------
__global__ __launch_bounds__(256) void caps_reduce_kernel(
    const float* __restrict__ partial, float* __restrict__ out)
{
  const int t = threadIdx.x;
  const int wv = t >> 6, ln = t & 63;
  const int pair = blockIdx.x*4 + wv;   // (b,o) pair, 2048 total
  const int b = pair >> 5, o = pair & 31;
  const int d = ln & 15, cg = ln >> 4;
  float s = 0.f;
  #pragma unroll 8
  for (int gg = cg; gg < 256; gg += 4)
    s += partial[(size_t)gg*32768 + (size_t)b*512 + o*16 + d];
  s += __shfl_xor(s, 16); s += __shfl_xor(s, 32);   // sum over cg groups
  float s2 = s*s;
  s2 += __shfl_xor(s2, 1); s2 += __shfl_xor(s2, 2);
  s2 += __shfl_xor(s2, 4); s2 += __shfl_xor(s2, 8); // sum over d
  float scale = s2/(1.0f+s2)/sqrtf(s2 + 1e-7f);
  if (ln < 16) out[(size_t)b*512 + o*16 + d] = scale*s;
}

extern "C" void kernel_launch(void* const* d_in, const int* in_sizes, int n_in,
                              void* d_out, int out_size, void* d_ws, size_t ws_size,
                              hipStream_t stream) {
  const float* x = (const float*)d_in[0];   // [64,2048,16]
  const float* W = (const float*)d_in[1];   // [1,2048,32,16,16]
  if (in_sizes[0] != 64*2048*16) { const float* tmp = x; x = W; W = tmp; }
  float* out = (float*)d_out;               // [64,32,16]

  float* partial = (float*)d_ws;            // 256*32768 f32 = 32 MB
  float* c2      = partial + (size_t)256*32768;  // 64*2048*32 f32 = 16 MB

  caps_c2_kernel<<<2048, 256, 0, stream>>>(x, W, c2);
  caps_main_kernel<<<512, 512, 0, stream>>>(x, W, c2, partial);
  caps_reduce_kernel<<<512, 256, 0, stream>>>(partial, out);
}